// Round 1
// baseline (680.256 us; speedup 1.0000x reference)
//
#include <hip/hip_runtime.h>

// Flash attention fwd: SQ=2048, B=2, H=16, D=64, fp32 in/out, bool mask.
// S^T formulation: q lives on the MFMA lane dim -> per-lane softmax,
// b64 P writes, contiguous b128 P/V^T frag reads. f16 MFMA, fp32 accum.

using half8  = __attribute__((ext_vector_type(8))) _Float16;
using half4  = __attribute__((ext_vector_type(4))) _Float16;
using float4v = __attribute__((ext_vector_type(4))) float;
using uint4v  = __attribute__((ext_vector_type(4))) unsigned int;

constexpr int SQn = 2048;
constexpr int BHn = 32;   // B*H
constexpr int Dn  = 64;
constexpr int KT  = 64;   // k-tile
constexpr int QTB = 128;  // q rows per block
constexpr int WQ  = 32;   // q rows per wave

constexpr int KSTR = 72;  // K_lds row stride (halves), 16B-aligned rows, pad vs conflicts
constexpr int VSTR = 72;  // Vt_lds row stride
constexpr int PSTR = 72;  // P_lds row stride

__global__ __launch_bounds__(256, 2)
void fa_fwd_kernel(const float* __restrict__ Qg, const float* __restrict__ Kg,
                   const float* __restrict__ Vg, const unsigned char* __restrict__ Mg,
                   float* __restrict__ Og)
{
    __shared__ _Float16 Kl[KT * KSTR];        // [k][d]   9216 B
    __shared__ _Float16 Vl[Dn * VSTR];        // [d][k]   9216 B (transposed)
    __shared__ _Float16 Pl[4][WQ * PSTR];     // per-wave [q][k]  18432 B

    const int tid  = threadIdx.x;
    const int wid  = tid >> 6;
    const int lane = tid & 63;
    const int l15  = lane & 15;
    const int quad = lane >> 4;

    const int bid = blockIdx.x;
    const int bh  = bid >> 4;            // 0..31
    const int qt0 = (bid & 15) * QTB;    // block q start
    const int qw0 = qt0 + wid * WQ;      // wave q start

    // ---- Q fragments (B-operand of S^T = K*Q^T), pre-scaled by 1/sqrt(D) ----
    // B-frag: lane l15 -> q, quad*8+j -> d (contraction)
    half8 qf[2][2];
#pragma unroll
    for (int qq = 0; qq < 2; ++qq) {
        const int qrow = qw0 + qq * 16 + l15;
        const float* src = Qg + ((size_t)qrow * BHn + bh) * Dn + quad * 8;
#pragma unroll
        for (int c = 0; c < 2; ++c) {
            float4v f0 = *(const float4v*)(src + 32 * c);
            float4v f1 = *(const float4v*)(src + 32 * c + 4);
            half8 h;
#pragma unroll
            for (int j = 0; j < 4; ++j) {
                h[j]     = (_Float16)(f0[j] * 0.125f);
                h[j + 4] = (_Float16)(f1[j] * 0.125f);
            }
            qf[qq][c] = h;
        }
    }

    // ---- running softmax state (per q = per l15-lane; redundant across quads) ----
    float mrun[2] = { -1e30f, -1e30f };
    float lrun[2] = { 0.f, 0.f };
    float4v otf[4][2];   // O^T frags: [d-tile][q-tile], row=d=16td+4quad+r, col=q=l15
#pragma unroll
    for (int td = 0; td < 4; ++td)
#pragma unroll
        for (int qq = 0; qq < 2; ++qq)
            otf[td][qq] = float4v{0.f, 0.f, 0.f, 0.f};

    // ---- staging registers (single-buffered prefetch) ----
    float4v kreg[4], vreg[4];
    uint4v  mreg[2];

    auto prefetch = [&](int kt) {
        const int k0 = kt * KT;
#pragma unroll
        for (int p = 0; p < 4; ++p) {
            const int flat = p * 256 + tid;
            const int krow = flat >> 4;
            const int d4   = (flat & 15) * 4;
            const size_t off = ((size_t)(k0 + krow) * BHn + bh) * Dn + d4;
            kreg[p] = *(const float4v*)(Kg + off);
            vreg[p] = *(const float4v*)(Vg + off);
        }
        // wave's mask slice: 32 q-rows x 64 k = 2KB; lane: row=lane>>1, 32B half
        const unsigned char* mp = Mg + (size_t)bh * SQn * SQn
                                + (size_t)(qw0 + (lane >> 1)) * SQn + k0 + (lane & 1) * 32;
        mreg[0] = __builtin_nontemporal_load((const uint4v*)mp);
        mreg[1] = __builtin_nontemporal_load((const uint4v*)(mp + 16));
    };

    prefetch(0);

    for (int kt = 0; kt < SQn / KT; ++kt) {
        // ---- commit staged tile to LDS (fp32 -> f16) ----
#pragma unroll
        for (int p = 0; p < 4; ++p) {
            const int flat = p * 256 + tid;
            const int krow = flat >> 4;
            const int d4   = (flat & 15) * 4;
            half4 kh;
#pragma unroll
            for (int i = 0; i < 4; ++i) kh[i] = (_Float16)kreg[p][i];
            *(half4*)&Kl[krow * KSTR + d4] = kh;
#pragma unroll
            for (int i = 0; i < 4; ++i)
                Vl[(d4 + i) * VSTR + krow] = (_Float16)vreg[p][i];
        }

        // ---- mask fast-path check (wave-uniform) ----
        unsigned int orv = mreg[0][0] | mreg[0][1] | mreg[0][2] | mreg[0][3]
                         | mreg[1][0] | mreg[1][1] | mreg[1][2] | mreg[1][3];
        const bool mflag = (__ballot(orv != 0u) != 0ull);
        if (mflag) {  // stage mask bytes into (not-yet-used) P region
            char* mr = (char*)&Pl[wid][0];
            *(uint4v*)(mr + (lane >> 1) * 64 + (lane & 1) * 32)      = mreg[0];
            *(uint4v*)(mr + (lane >> 1) * 64 + (lane & 1) * 32 + 16) = mreg[1];
        }

        __syncthreads();   // K/V tile visible to all waves

        prefetch((kt + 1) & 31);   // overlap next-tile loads with compute

        // ---- S^T = K * Q^T : st[tk][qq], row=k_local=16tk+4quad+r, col=q=l15 ----
        float4v st[4][2];
#pragma unroll
        for (int tk = 0; tk < 4; ++tk) {
            st[tk][0] = float4v{0.f, 0.f, 0.f, 0.f};
            st[tk][1] = float4v{0.f, 0.f, 0.f, 0.f};
#pragma unroll
            for (int c = 0; c < 2; ++c) {
                half8 ka = *(const half8*)&Kl[(tk * 16 + l15) * KSTR + c * 32 + quad * 8];
                st[tk][0] = __builtin_amdgcn_mfma_f32_16x16x32_f16(ka, qf[0][c], st[tk][0], 0, 0, 0);
                st[tk][1] = __builtin_amdgcn_mfma_f32_16x16x32_f16(ka, qf[1][c], st[tk][1], 0, 0, 0);
            }
        }

        // ---- mask apply (taken only if any mask bit set in tile) ----
        if (mflag) {
            const unsigned char* mr = (const unsigned char*)&Pl[wid][0];
#pragma unroll
            for (int qq = 0; qq < 2; ++qq)
#pragma unroll
                for (int tk = 0; tk < 4; ++tk)
#pragma unroll
                    for (int r = 0; r < 4; ++r)
                        if (mr[(qq * 16 + l15) * 64 + tk * 16 + quad * 4 + r])
                            st[tk][qq][r] = -10000.f;
        }

        // ---- online softmax (q is lane-resident: per-lane + 2 shuffles) ----
#pragma unroll
        for (int qq = 0; qq < 2; ++qq) {
            float mx = -1e30f;
#pragma unroll
            for (int tk = 0; tk < 4; ++tk)
#pragma unroll
                for (int r = 0; r < 4; ++r) mx = fmaxf(mx, st[tk][qq][r]);
            mx = fmaxf(mx, __shfl_xor(mx, 16));
            mx = fmaxf(mx, __shfl_xor(mx, 32));
            const float mnew  = fmaxf(mrun[qq], mx);
            const float alpha = __expf(mrun[qq] - mnew);
            mrun[qq] = mnew;

            float ls = 0.f;
#pragma unroll
            for (int tk = 0; tk < 4; ++tk) {
                half4 ph;
#pragma unroll
                for (int r = 0; r < 4; ++r) {
                    const float p = __expf(st[tk][qq][r] - mnew);
                    ls += p;
                    ph[r] = (_Float16)p;
                }
                // P[q][k]: 4 consecutive k per lane -> one b64 write
                *(half4*)&Pl[wid][(qq * 16 + l15) * PSTR + tk * 16 + quad * 4] = ph;
            }
            ls += __shfl_xor(ls, 16);
            ls += __shfl_xor(ls, 32);
            lrun[qq] = lrun[qq] * alpha + ls;

#pragma unroll
            for (int td = 0; td < 4; ++td)
#pragma unroll
                for (int r = 0; r < 4; ++r) otf[td][qq][r] *= alpha;
        }

        // ---- O^T += V^T * P^T ----
#pragma unroll
        for (int c2 = 0; c2 < 2; ++c2) {
            half8 pb0 = *(const half8*)&Pl[wid][(l15) * PSTR + c2 * 32 + quad * 8];
            half8 pb1 = *(const half8*)&Pl[wid][(16 + l15) * PSTR + c2 * 32 + quad * 8];
#pragma unroll
            for (int td = 0; td < 4; ++td) {
                half8 va = *(const half8*)&Vl[(td * 16 + l15) * VSTR + c2 * 32 + quad * 8];
                otf[td][0] = __builtin_amdgcn_mfma_f32_16x16x32_f16(va, pb0, otf[td][0], 0, 0, 0);
                otf[td][1] = __builtin_amdgcn_mfma_f32_16x16x32_f16(va, pb1, otf[td][1], 0, 0, 0);
            }
        }

        __syncthreads();   // compute done before next tile overwrites K/V LDS
    }

    // ---- epilogue: normalize by l, store ctx[q][b][h*64+d] ----
    const int b = bh >> 4, h = bh & 15;
#pragma unroll
    for (int qq = 0; qq < 2; ++qq) {
        const float inv  = 1.0f / lrun[qq];
        const int   qrow = qw0 + qq * 16 + l15;
        float* dst = Og + ((size_t)qrow * 2 + b) * 1024 + h * 64 + quad * 4;
#pragma unroll
        for (int td = 0; td < 4; ++td) {
            float4v o;
#pragma unroll
            for (int r = 0; r < 4; ++r) o[r] = otf[td][qq][r] * inv;
            *(float4v*)(dst + td * 16) = o;
        }
    }
}

extern "C" void kernel_launch(void* const* d_in, const int* in_sizes, int n_in,
                              void* d_out, int out_size, void* d_ws, size_t ws_size,
                              hipStream_t stream) {
    const float* Q = (const float*)d_in[0];
    const float* K = (const float*)d_in[1];
    const float* V = (const float*)d_in[2];
    const unsigned char* M = (const unsigned char*)d_in[3];
    float* O = (float*)d_out;
    // 512 blocks (16 q-tiles x 32 bh), 256 threads, 36.9 KB static LDS -> 2 blocks/CU
    hipLaunchKernelGGL(fa_fwd_kernel, dim3(16 * BHn), dim3(256), 0, stream, Q, K, V, M, O);
}